// Round 2
// baseline (193.252 us; speedup 1.0000x reference)
//
#include <hip/hip_runtime.h>
#include <stdint.h>

typedef __attribute__((ext_vector_type(8))) short short8;
typedef __attribute__((ext_vector_type(16))) float f32x16;

#define LOG2E 1.4426950408889634f

__device__ inline float fast_exp2(float x) {
#if __has_builtin(__builtin_amdgcn_exp2f)
  return __builtin_amdgcn_exp2f(x);
#else
  float r;
  asm volatile("v_exp_f32 %0, %1" : "=v"(r) : "v"(x));
  return r;
#endif
}

// Split 8 f32 (optionally scaled) into bf16 hi + bf16 lo (truncation split;
// |x - hi - lo| <= 2^-16 |x|).
__device__ inline void split8(float x0, float x1, float x2, float x3,
                              float x4, float x5, float x6, float x7,
                              float scale, short8& hi, short8& lo) {
  float xs[8] = {x0, x1, x2, x3, x4, x5, x6, x7};
#pragma unroll
  for (int i = 0; i < 8; ++i) {
    float v = xs[i] * scale;
    unsigned u = __float_as_uint(v);
    float hf = __uint_as_float(u & 0xffff0000u);
    float rr = v - hf;  // exact
    hi[i] = (short)(u >> 16);
    lo[i] = (short)(__float_as_uint(rr) >> 16);
  }
}

// ---------------------------------------------------------------------------
// Preprocess: s[m] = exp(-||y_m||^2/2) * w[m];  pref[n] = exp(-||x_n||^2/2)
// ---------------------------------------------------------------------------
__global__ __launch_bounds__(256) void gk_prep(
    const float* __restrict__ Xnew, const float* __restrict__ Xtr,
    const float* __restrict__ w, float* __restrict__ s,
    float* __restrict__ pref, int M, int N) {
  int row = blockIdx.x * 4 + (threadIdx.x >> 6);
  int lane = threadIdx.x & 63;
  if (row >= M + N) return;
  const float* src =
      (row < M) ? (Xtr + (size_t)row * 128) : (Xnew + (size_t)(row - M) * 128);
  float2 v = *(const float2*)(src + lane * 2);
  float ss = v.x * v.x + v.y * v.y;
#pragma unroll
  for (int o = 32; o >= 1; o >>= 1) ss += __shfl_xor(ss, o, 64);
  if (lane == 0) {
    float e = expf(-0.5f * ss);
    if (row < M)
      s[row] = e * w[row];
    else
      pref[row - M] = e;
  }
}

// ---------------------------------------------------------------------------
// Main kernel: 4 waves, 256 output cols (X_new panel in registers as bf16
// hi/lo scaled by log2e), streaming 64 X_train rows/iter through
// DOUBLE-BUFFERED LDS with ONE barrier per iter; staging (convert+write),
// next-tile global-load issue, MFMA and exp2-epilogue all live in a single
// phase so the scheduler overlaps them across the CU's 8 resident waves.
// Safety: writes to buf[(it+1)&1] follow the barrier at top of phase it,
// which guarantees all waves completed phase it-1 (the last readers of that
// buffer).
// ---------------------------------------------------------------------------
__global__ __launch_bounds__(256, 2) void gk_main(
    const float* __restrict__ Xnew, const float* __restrict__ Xtr,
    const float* __restrict__ s, const float* __restrict__ pref,
    float* __restrict__ out, int N, int M, int mchunk) {
  // [2 bufs][hi 16K | lo 16K]  = 64 KiB total (static LDS cap)
  __shared__ __attribute__((aligned(16))) char lds[2][32768];

  const int t = threadIdx.x;
  const int l = t & 63;
  const int w = t >> 6;
  const int lrow = l & 31;  // A row / B col within 32-frag
  const int lk = l >> 5;    // k half

  const int n0 = blockIdx.x * 256;
  const int M0 = blockIdx.y * mchunk;
  const int iters = mchunk >> 6;

  // ---- load B (X_new panel) once into registers, scaled by LOG2E ----------
  short8 bh[2][8], bl[2][8];
  {
    const int colbase = n0 + w * 64;
#pragma unroll
    for (int nf = 0; nf < 2; ++nf) {
      int col = colbase + nf * 32 + lrow;
      const float* p = Xnew + (size_t)col * 128 + lk * 8;
#pragma unroll
      for (int kf = 0; kf < 8; ++kf) {
        float4 f0 = *(const float4*)(p + kf * 16);
        float4 f1 = *(const float4*)(p + kf * 16 + 4);
        split8(f0.x, f0.y, f0.z, f0.w, f1.x, f1.y, f1.z, f1.w, LOG2E,
               bh[nf][kf], bl[nf][kf]);
      }
    }
  }

  // lane-constant pieces of the XOR swizzle (row steps by 8/16 per lane-chunk,
  // so row&7 is lane-invariant on both the read and write paths)
  const int wrow = t >> 4;   // write row base (j adds 16 -> row&7 invariant)
  const int woct = t & 15;   // 16B granule within row
  const unsigned wr_off0 = ((unsigned)wrow << 8) +
                           (((unsigned)woct << 4) ^ (((unsigned)wrow & 7u) << 4));
  const unsigned rd_xor = ((unsigned)lrow & 7u) << 4;

  float4 ga[4][2];  // staged f32 rows for the next tile
  float scur = 0.f, snxt = 0.f;

  // ---- prologue: tile 0 staged + written; tile 1 loads issued -------------
  {
    const float* abase = Xtr + (size_t)M0 * 128;
#pragma unroll
    for (int j = 0; j < 4; ++j) {
      const float* p = abase + (size_t)(wrow + j * 16) * 128 + woct * 8;
      ga[j][0] = *(const float4*)p;
      ga[j][1] = *(const float4*)(p + 4);
    }
    scur = s[M0 + l];
  }
  {
    char* base = lds[0];
#pragma unroll
    for (int j = 0; j < 4; ++j) {
      unsigned off = wr_off0 + (unsigned)(j << 12);  // j*16 rows * 256B
      short8 hi, lo;
      split8(ga[j][0].x, ga[j][0].y, ga[j][0].z, ga[j][0].w, ga[j][1].x,
             ga[j][1].y, ga[j][1].z, ga[j][1].w, 1.0f, hi, lo);
      *(short8*)(base + off) = hi;
      *(short8*)(base + 16384 + off) = lo;
    }
  }
  if (iters > 1) {
    const float* abase = Xtr + (size_t)(M0 + 64) * 128;
#pragma unroll
    for (int j = 0; j < 4; ++j) {
      const float* p = abase + (size_t)(wrow + j * 16) * 128 + woct * 8;
      ga[j][0] = *(const float4*)p;
      ga[j][1] = *(const float4*)(p + 4);
    }
    snxt = s[M0 + 64 + l];
  }

  float o0a = 0.f, o0b = 0.f, o1a = 0.f, o1b = 0.f;

#pragma unroll 1
  for (int it = 0; it < iters; ++it) {
    __syncthreads();  // buf[(it+1)&1]'s last readers (phase it-1) are done;
                      // also publishes buf[it&1] written in phase it-1.

    float snew = 0.f;
    // ---- stage next tile into the other buffer (overlaps with MFMAs) ------
    if (it + 1 < iters) {
      char* base = lds[(it + 1) & 1];
#pragma unroll
      for (int j = 0; j < 4; ++j) {
        unsigned off = wr_off0 + (unsigned)(j << 12);
        short8 hi, lo;
        split8(ga[j][0].x, ga[j][0].y, ga[j][0].z, ga[j][0].w, ga[j][1].x,
               ga[j][1].y, ga[j][1].z, ga[j][1].w, 1.0f, hi, lo);
        *(short8*)(base + off) = hi;
        *(short8*)(base + 16384 + off) = lo;
      }
      if (it + 2 < iters) {
        const float* abase = Xtr + (size_t)(M0 + (it + 2) * 64) * 128;
#pragma unroll
        for (int j = 0; j < 4; ++j) {
          const float* p = abase + (size_t)(wrow + j * 16) * 128 + woct * 8;
          ga[j][0] = *(const float4*)p;
          ga[j][1] = *(const float4*)(p + 4);
        }
        snew = s[M0 + (it + 2) * 64 + l];
      }
    }

    // ---- compute: 2 m-frags x 2 n-frags of 32x32, K=128, bf16x3 ----------
    const char* base = lds[it & 1];
#pragma unroll
    for (int mf = 0; mf < 2; ++mf) {
      f32x16 acc0 = {0, 0, 0, 0, 0, 0, 0, 0, 0, 0, 0, 0, 0, 0, 0, 0};
      f32x16 acc1 = {0, 0, 0, 0, 0, 0, 0, 0, 0, 0, 0, 0, 0, 0, 0, 0};
#pragma unroll
      for (int kf = 0; kf < 8; ++kf) {
        unsigned off = ((unsigned)(mf * 32 + lrow) << 8) +
                       (((unsigned)(kf * 32 + lk * 16)) ^ rd_xor);
        short8 ah = *(const short8*)(base + off);
        short8 al = *(const short8*)(base + 16384 + off);
        acc0 = __builtin_amdgcn_mfma_f32_32x32x16_bf16(ah, bh[0][kf], acc0, 0, 0, 0);
        acc1 = __builtin_amdgcn_mfma_f32_32x32x16_bf16(ah, bh[1][kf], acc1, 0, 0, 0);
        acc0 = __builtin_amdgcn_mfma_f32_32x32x16_bf16(ah, bl[0][kf], acc0, 0, 0, 0);
        acc1 = __builtin_amdgcn_mfma_f32_32x32x16_bf16(ah, bl[1][kf], acc1, 0, 0, 0);
        acc0 = __builtin_amdgcn_mfma_f32_32x32x16_bf16(al, bh[0][kf], acc0, 0, 0, 0);
        acc1 = __builtin_amdgcn_mfma_f32_32x32x16_bf16(al, bh[1][kf], acc1, 0, 0, 0);
      }
      // epilogue: exp2 + weighted row-sum. C/D layout (verified):
      // col = lane&31, row = (reg&3) + 8*(reg>>2) + 4*(lane>>5)
#pragma unroll
      for (int r = 0; r < 16; ++r) {
        int row = (r & 3) + 8 * (r >> 2) + 4 * lk;
        float sv = __shfl(scur, mf * 32 + row, 64);
        if (r & 1) {
          o0b += fast_exp2(acc0[r]) * sv;
          o1b += fast_exp2(acc1[r]) * sv;
        } else {
          o0a += fast_exp2(acc0[r]) * sv;
          o1a += fast_exp2(acc1[r]) * sv;
        }
      }
    }
    scur = snxt;
    snxt = snew;
  }

  // ---- cross-lane m-reduction (rows split across lane>>5) + atomic --------
  float out0 = o0a + o0b, out1 = o1a + o1b;
  out0 += __shfl_xor(out0, 32, 64);
  out1 += __shfl_xor(out1, 32, 64);
  if (l < 32) {
    int n = n0 + w * 64 + l;
    atomicAdd(out + n, pref[n] * out0);
    n += 32;
    atomicAdd(out + n, pref[n] * out1);
  }
}

extern "C" void kernel_launch(void* const* d_in, const int* in_sizes, int n_in,
                              void* d_out, int out_size, void* d_ws,
                              size_t ws_size, hipStream_t stream) {
  const float* Xnew = (const float*)d_in[0];
  const float* Xtr = (const float*)d_in[1];
  const float* wts = (const float*)d_in[2];
  float* out = (float*)d_out;

  const int N = in_sizes[0] / 128;  // 8192
  const int M = in_sizes[1] / 128;  // 32768

  float* s_ws = (float*)d_ws;   // [M]
  float* pref_ws = s_ws + M;    // [N]

  hipMemsetAsync(d_out, 0, (size_t)N * sizeof(float), stream);

  int rows = M + N;
  gk_prep<<<dim3((rows + 3) / 4), 256, 0, stream>>>(Xnew, Xtr, wts, s_ws,
                                                    pref_ws, M, N);

  const int SPLIT = 16;
  dim3 grid(N / 256, SPLIT);
  gk_main<<<grid, 256, 0, stream>>>(Xnew, Xtr, s_ws, pref_ws, out, N, M,
                                    M / SPLIT);
}